// Round 7
// baseline (1187.459 us; speedup 1.0000x reference)
//
#include <hip/hip_runtime.h>
#include <hip/hip_bf16.h>

typedef __hip_bfloat16 bf16;
typedef __bf16 v8bf __attribute__((ext_vector_type(8)));
typedef float f32x4 __attribute__((ext_vector_type(4)));

#define N_AG 24576
#define N3 8192

struct __align__(8) bf4 { bf16 x, y, z, w; };
__device__ __forceinline__ bf4 mk4(float a, float b, float c, float d) {
  bf4 r{__float2bfloat16(a), __float2bfloat16(b), __float2bfloat16(c), __float2bfloat16(d)};
  return r;
}

// ---------------- epilogue modes ----------------
enum {
  EPI_RELU_BIAS = 0,  // Cout(bf16) = relu(v + bias)
  EPI_BIAS      = 1,  // Cout(bf16) = v + bias
  EPI_ACC_INIT  = 2,  // accbuf(f32) = v + bias
  EPI_ACC_ADD   = 3,  // accbuf(f32) += v + bias
  EPI_FINAL     = 4   // CoutF(f32) = accbuf + v + bias + resid
};

// async 16B/lane global->LDS DMA; LDS dest = wave-uniform base + lane*16
__device__ __forceinline__ void gl_lds16(const bf16* g, short* l) {
  __builtin_amdgcn_global_load_lds(
      (const __attribute__((address_space(1))) unsigned int*)g,
      (__attribute__((address_space(3))) unsigned int*)l, 16, 0, 0);
}

// ---------------- GEMM: C[M,Nc] = A[M,K] @ B[K,Nc], B given transposed ----------------
// A, Bt bf16; bias/acc/resid/final f32. 128x128 tile, BK=32, 4 waves, 4x4
// mfma_f32_16x16x32_bf16 (C/D: col=lane&15, row=quad*4+reg).
// LDS layout (conflict-free under DMA constraint): 16B slot = kchunk*128 + row.
// Wave w DMAs k-chunk w (8 elems) for rows lane and 64+lane (2 issues per tile).
// Frag read addr = quad*2048 + row*16 B -> 16 consecutive rows cover all 32
// banks twice = 2-way alias = free (m136).  Grid: x = row tiles (gridDim.x
// multiple of 8 -> col tiles of one row share an XCD for L2 A reuse).
template<int EPI>
__global__ __launch_bounds__(256)
void gemm_k(const bf16* __restrict__ A, int lda,
            const bf16* __restrict__ Bt, int ldb, long bTs,
            const float* __restrict__ bias, long biasTs,
            float* __restrict__ accbuf,
            bf16* __restrict__ Cout, int ldc,
            const float* __restrict__ resid,
            float* __restrict__ CoutF,
            int K, int Nc)
{
  __shared__ __align__(16) short As[4 * 128 * 8];
  __shared__ __align__(16) short Bs[4 * 128 * 8];

  const int tid  = threadIdx.x;
  const int lane = tid & 63;
  const int w    = tid >> 6;
  const int quad = lane >> 4;
  const int l15  = lane & 15;
  const int row0 = blockIdx.x * 128;
  const int col0 = blockIdx.y * 128;
  const int t    = row0 >> 13;

  const bf16*  Bp = Bt + (long)t * bTs;
  const float* bp = bias ? bias + (long)t * biasTs : nullptr;

  f32x4 acc[4][4];
  const f32x4 zero = {0.f, 0.f, 0.f, 0.f};
#pragma unroll
  for (int i = 0; i < 4; ++i)
#pragma unroll
    for (int j = 0; j < 4; ++j) acc[i][j] = zero;

  // staging: wave w covers k-chunk w, rows lane (issue 0) and 64+lane (issue 1)
  const bf16* aG = A  + (long)(row0 + lane) * lda + w * 8;
  const bf16* bG = Bp + (long)(col0 + lane) * ldb + w * 8;
  short* AsW = As + w * 128 * 8;     // slot base = kchunk w, row 0
  short* BsW = Bs + w * 128 * 8;

  const int wr = (w >> 1) * 64;
  const int wc = (w & 1) * 64;

  for (int k0 = 0; k0 < K; k0 += 32) {
    gl_lds16(aG + k0,                  AsW);
    gl_lds16(aG + k0 + (long)64 * lda, AsW + 64 * 8);
    gl_lds16(bG + k0,                  BsW);
    gl_lds16(bG + k0 + (long)64 * ldb, BsW + 64 * 8);
    __syncthreads();

    v8bf af[4], bfm[4];
#pragma unroll
    for (int i = 0; i < 4; ++i) {
      af[i]  = *(const v8bf*)&As[(quad * 128 + wr + i * 16 + l15) * 8];
      bfm[i] = *(const v8bf*)&Bs[(quad * 128 + wc + i * 16 + l15) * 8];
    }
#pragma unroll
    for (int i = 0; i < 4; ++i)
#pragma unroll
      for (int j = 0; j < 4; ++j)
        acc[i][j] = __builtin_amdgcn_mfma_f32_16x16x32_bf16(af[i], bfm[j], acc[i][j], 0, 0, 0);
    __syncthreads();
  }

#pragma unroll
  for (int ct = 0; ct < 4; ++ct) {
    const int col = col0 + wc + ct * 16 + l15;
    const float bv = bp ? bp[col] : 0.f;
#pragma unroll
    for (int rt = 0; rt < 4; ++rt) {
#pragma unroll
      for (int i = 0; i < 4; ++i) {
        const int row = row0 + wr + rt * 16 + quad * 4 + i;
        float v = acc[rt][ct][i] + bv;
        if constexpr (EPI == EPI_RELU_BIAS) {
          Cout[(long)row * ldc + col] = __float2bfloat16(v > 0.f ? v : 0.f);
        } else if constexpr (EPI == EPI_BIAS) {
          Cout[(long)row * ldc + col] = __float2bfloat16(v);
        } else if constexpr (EPI == EPI_ACC_INIT) {
          accbuf[(long)row * Nc + col] = v;
        } else if constexpr (EPI == EPI_ACC_ADD) {
          accbuf[(long)row * Nc + col] += v;
        } else {  // EPI_FINAL
          CoutF[(long)row * ldc + col] =
              accbuf[(long)row * Nc + col] + v + resid[(long)row * ldc + col];
        }
      }
    }
  }
}

// ---------------- weight transpose+cast: src f32 [K,Nc] -> dst bf16 [Nc,K], batched z ----------------
__global__ __launch_bounds__(256)
void transpose_k(const float* __restrict__ src, bf16* __restrict__ dst,
                 int K, int Nc, long sB, long dB)
{
  __shared__ bf16 tile[32][33];
  const int b = blockIdx.z;
  const float* s = src + (long)b * sB;
  bf16* d = dst + (long)b * dB;
  const int kb = blockIdx.y * 32, nb = blockIdx.x * 32;
  const int tx = threadIdx.x & 31, ty = threadIdx.x >> 5;
#pragma unroll
  for (int i = 0; i < 32; i += 8)
    tile[ty + i][tx] = __float2bfloat16(s[(long)(kb + ty + i) * Nc + nb + tx]);
  __syncthreads();
#pragma unroll
  for (int i = 0; i < 32; i += 8)
    d[(long)(nb + ty + i) * K + kb + tx] = tile[tx][ty + i];
}

// ---------------- f32 -> bf16 cast, 4 elems/thread ----------------
__global__ __launch_bounds__(256)
void cast_k(const float* __restrict__ src, bf16* __restrict__ dst)
{
  const long i = (long)blockIdx.x * 256 + threadIdx.x;
  const float4 v = ((const float4*)src)[i];
  ((bf4*)dst)[i] = mk4(v.x, v.y, v.z, v.w);
}

// ---------------- wave-wide reduce (all lanes get totals) ----------------
__device__ __forceinline__ void wave_reduce2(float& s, float& q) {
#pragma unroll
  for (int off = 32; off > 0; off >>= 1) {
    s += __shfl_xor(s, off, 64);
    q += __shfl_xor(q, off, 64);
  }
}

// ---------------- LN over concat([f, x, f]) width 768; one wave per row ----------------
__global__ __launch_bounds__(256)
void ln_cat3_k(const float* __restrict__ feat, const float* __restrict__ x,
               const int* __restrict__ srcIdx,
               const float* __restrict__ ls, const float* __restrict__ lb,
               bf16* __restrict__ out)
{
  const int w = threadIdx.x >> 6, lane = threadIdx.x & 63;
  const int r = blockIdx.x * 4 + w;
  const int src = srcIdx[r];
  const float4 f4 = ((const float4*)(feat + (long)src * 256))[lane];
  const float4 x4 = ((const float4*)(x + (long)r * 256))[lane];
  float s = 2.f * (f4.x + f4.y + f4.z + f4.w) + (x4.x + x4.y + x4.z + x4.w);
  float q = 2.f * (f4.x * f4.x + f4.y * f4.y + f4.z * f4.z + f4.w * f4.w) +
            (x4.x * x4.x + x4.y * x4.y + x4.z * x4.z + x4.w * x4.w);
  wave_reduce2(s, q);
  const float mu  = s * (1.f / 768.f);
  const float var = q * (1.f / 768.f) - mu * mu;
  const float inv = rsqrtf(var + 1e-5f);
  const float4 s0 = ((const float4*)ls)[lane],        b0 = ((const float4*)lb)[lane];
  const float4 s1 = ((const float4*)(ls + 256))[lane], b1 = ((const float4*)(lb + 256))[lane];
  const float4 s2 = ((const float4*)(ls + 512))[lane], b2 = ((const float4*)(lb + 512))[lane];
  bf4* o = (bf4*)(out + (long)r * 768);
  o[lane] = mk4((f4.x - mu) * inv * s0.x + b0.x, (f4.y - mu) * inv * s0.y + b0.y,
                (f4.z - mu) * inv * s0.z + b0.z, (f4.w - mu) * inv * s0.w + b0.w);
  o[64 + lane] = mk4((x4.x - mu) * inv * s1.x + b1.x, (x4.y - mu) * inv * s1.y + b1.y,
                     (x4.z - mu) * inv * s1.z + b1.z, (x4.w - mu) * inv * s1.w + b1.w);
  o[128 + lane] = mk4((f4.x - mu) * inv * s2.x + b2.x, (f4.y - mu) * inv * s2.y + b2.y,
                      (f4.z - mu) * inv * s2.z + b2.z, (f4.w - mu) * inv * s2.w + b2.w);
}

// ---------------- LN over concat([f, x]) width 512; one wave per row ----------------
__global__ __launch_bounds__(256)
void ln_cat2_k(const float* __restrict__ feat, const float* __restrict__ x,
               const int* __restrict__ srcIdx,
               const float* __restrict__ ls, const float* __restrict__ lb,
               bf16* __restrict__ out)
{
  const int w = threadIdx.x >> 6, lane = threadIdx.x & 63;
  const int r = blockIdx.x * 4 + w;
  const int src = srcIdx[r];
  const float4 f4 = ((const float4*)(feat + (long)src * 256))[lane];
  const float4 x4 = ((const float4*)(x + (long)r * 256))[lane];
  float s = (f4.x + f4.y + f4.z + f4.w) + (x4.x + x4.y + x4.z + x4.w);
  float q = (f4.x * f4.x + f4.y * f4.y + f4.z * f4.z + f4.w * f4.w) +
            (x4.x * x4.x + x4.y * x4.y + x4.z * x4.z + x4.w * x4.w);
  wave_reduce2(s, q);
  const float mu  = s * (1.f / 512.f);
  const float var = q * (1.f / 512.f) - mu * mu;
  const float inv = rsqrtf(var + 1e-5f);
  const float4 s0 = ((const float4*)ls)[lane],        b0 = ((const float4*)lb)[lane];
  const float4 s1 = ((const float4*)(ls + 256))[lane], b1 = ((const float4*)(lb + 256))[lane];
  bf4* o = (bf4*)(out + (long)r * 512);
  o[lane] = mk4((f4.x - mu) * inv * s0.x + b0.x, (f4.y - mu) * inv * s0.y + b0.y,
                (f4.z - mu) * inv * s0.z + b0.z, (f4.w - mu) * inv * s0.w + b0.w);
  o[64 + lane] = mk4((x4.x - mu) * inv * s1.x + b1.x, (x4.y - mu) * inv * s1.y + b1.y,
                     (x4.z - mu) * inv * s1.z + b1.z, (x4.w - mu) * inv * s1.w + b1.w);
}

// ---------------- FFN layernorm width 256: f32 in, bf16 out; one wave per row ----------------
__global__ __launch_bounds__(256)
void ln_ffn_k(const float* __restrict__ ob, const float* __restrict__ ls,
              const float* __restrict__ lb, bf16* __restrict__ y, long lsStride)
{
  const int w = threadIdx.x >> 6, lane = threadIdx.x & 63;
  const int r = blockIdx.x * 4 + w;
  const long po = (long)(r >> 13) * lsStride;
  const float4 v4 = ((const float4*)(ob + (long)r * 256))[lane];
  float s = v4.x + v4.y + v4.z + v4.w;
  float q = v4.x * v4.x + v4.y * v4.y + v4.z * v4.z + v4.w * v4.w;
  wave_reduce2(s, q);
  const float mu  = s * (1.f / 256.f);
  const float var = q * (1.f / 256.f) - mu * mu;
  const float inv = rsqrtf(var + 1e-5f);
  const float4 s0 = ((const float4*)(ls + po))[lane];
  const float4 b0 = ((const float4*)(lb + po))[lane];
  ((bf4*)(y + (long)r * 256))[lane] =
      mk4((v4.x - mu) * inv * s0.x + b0.x, (v4.y - mu) * inv * s0.y + b0.y,
          (v4.z - mu) * inv * s0.z + b0.z, (v4.w - mu) * inv * s0.w + b0.w);
}

// ---------------- g = silu(g) * u, 4 elems/thread ----------------
__global__ __launch_bounds__(256)
void silu_mul_k(bf16* __restrict__ g, const bf16* __restrict__ u)
{
  const long i = (long)blockIdx.x * 256 + threadIdx.x;
  const bf4 g4 = ((const bf4*)g)[i];
  const bf4 u4 = ((const bf4*)u)[i];
  float a = __bfloat162float(g4.x), b = __bfloat162float(g4.y);
  float c = __bfloat162float(g4.z), d = __bfloat162float(g4.w);
  a = a / (1.f + expf(-a)) * __bfloat162float(u4.x);
  b = b / (1.f + expf(-b)) * __bfloat162float(u4.y);
  c = c / (1.f + expf(-c)) * __bfloat162float(u4.z);
  d = d / (1.f + expf(-d)) * __bfloat162float(u4.w);
  ((bf4*)g)[i] = mk4(a, b, c, d);
}

// ---------------- sentinel fill (diagnostic) ----------------
__global__ __launch_bounds__(256)
void fill_k(float* __restrict__ p, int n)
{
  const int i = blockIdx.x * 256 + threadIdx.x;
  if (i < n) p[i] = 2.0f;
}

// ---------------- host ----------------
extern "C" void kernel_launch(void* const* d_in, const int* in_sizes, int n_in,
                              void* d_out, int out_size, void* d_ws, size_t ws_size,
                              hipStream_t stream)
{
  const float* agent_x  = (const float*)d_in[0];
  const float* lane_x   = (const float*)d_in[1];
  const float* poly_x   = (const float*)d_in[2];
  const int*   l2a_src  = (const int*)d_in[3];
  const int*   g2a_src  = (const int*)d_in[4];
  const int*   other_src= (const int*)d_in[5];
  const float* self_W   = (const float*)d_in[6];
  const float* self_b   = (const float*)d_in[7];
  const float* out_W    = (const float*)d_in[8];
  const float* out_b    = (const float*)d_in[9];
  const float* ffn_ln_s = (const float*)d_in[10];
  const float* ffn_ln_b = (const float*)d_in[11];
  const float* ffn_w1   = (const float*)d_in[12];
  const float* ffn_b1   = (const float*)d_in[13];
  const float* ffn_w2   = (const float*)d_in[14];
  const float* ffn_b2   = (const float*)d_in[15];
  const float* ffn_w3   = (const float*)d_in[16];
  const float* ffn_b3   = (const float*)d_in[17];
  const float* l2a_ln_s = (const float*)d_in[18];
  const float* l2a_ln_b = (const float*)d_in[19];
  const float* l2a_w1   = (const float*)d_in[20];
  const float* l2a_b1   = (const float*)d_in[21];
  const float* l2a_w2   = (const float*)d_in[22];
  const float* l2a_b2   = (const float*)d_in[23];
  const float* g2a_ln_s = (const float*)d_in[24];
  const float* g2a_ln_b = (const float*)d_in[25];
  const float* g2a_w1   = (const float*)d_in[26];
  const float* g2a_b1   = (const float*)d_in[27];
  const float* g2a_w2   = (const float*)d_in[28];
  const float* g2a_b2   = (const float*)d_in[29];
  const float* oth_ln_s = (const float*)d_in[30];
  const float* oth_ln_b = (const float*)d_in[31];
  const float* oth_w1   = (const float*)d_in[32];
  const float* oth_b1   = (const float*)d_in[33];
  const float* oth_w2   = (const float*)d_in[34];
  const float* oth_b2   = (const float*)d_in[35];

  float* outp = (float*)d_out;
  const dim3 B256(256);

  // W^T element offsets within the hoisted wT block (8,323,072 elems = 16,646,144 B)
  const long SELF_WT = 0,        L2A_W1T = 196608,  L2A_W2T = 983040;
  const long G2A_W1T = 1245184,  G2A_W2T = 1769472;
  const long OTH_W1T = 2031616,  OTH_W2T = 4390912, OUT_WT = 5177344;
  const long FFN_W1T = 5963776,  FFN_W3T = 6750208, FFN_W2T = 7536640;

  const size_t TIER_A = 155058176;  // full-N hoisted (PROVEN: fired in R5/R6)
  const size_t TIER_B = 62783488;   // per-type hoisted
  const size_t TIER_C = 12058624;   // chunked, per-stage transposes

  if (ws_size >= TIER_B) {
    // ================= hoisted tiers (A: full-N, B: per-type) =================
    const bool full = ws_size >= TIER_A;
    const int  CH   = full ? N_AG : N3;
    char* base = (char*)d_ws;
    bf16*  wT     = (bf16*)base;
    bf16*  nbuf   = (bf16*)(base + 16646144L);
    bf16*  bbuf   = (bf16*)(base + 16646144L + (long)CH * 1536);
    bf16*  h1     = (bf16*)(base + 16646144L + (long)CH * 2048);
    float* outF32 = (float*)(base + 16646144L + (long)CH * 4096);
    bf16*  ybuf   = (bf16*)(base + 16646144L + (long)CH * 5120);
    bf16*  xbf    = h1;     // bf16 cast of chunk agent rows (dead before h1 written)
    bf16*  g_pre  = h1;
    bf16*  u_pre  = nbuf;   // nbuf+bbuf contiguous = CH x 1024 bf16

    // ---- transpose all weights once ----
    auto TRB = [&](const float* s, long dOff, int K, int Nc, long sB, long dB, int b) {
      transpose_k<<<dim3(Nc / 32, K / 32, b), B256, 0, stream>>>(s, wT + dOff, K, Nc, sB, dB);
    };
    TRB(self_W, SELF_WT, 256, 256,  65536, 65536, 3);
    TRB(l2a_w1, L2A_W1T, 768, 1024, 0, 0, 1);
    TRB(l2a_w2, L2A_W2T, 1024, 256, 0, 0, 1);
    TRB(g2a_w1, G2A_W1T, 512, 1024, 0, 0, 1);
    TRB(g2a_w2, G2A_W2T, 1024, 256, 0, 0, 1);
    TRB(oth_w1, OTH_W1T, 768, 1024, 786432, 786432, 3);
    TRB(oth_w2, OTH_W2T, 1024, 256, 262144, 262144, 3);
    TRB(out_W,  OUT_WT,  1024, 256, 262144, 262144, 3);
    TRB(ffn_w1, FFN_W1T, 256, 1024, 262144, 262144, 3);
    TRB(ffn_w3, FFN_W3T, 256, 1024, 262144, 262144, 3);
    TRB(ffn_w2, FFN_W2T, 1024, 256, 262144, 262144, 3);

    const int nOuter = full ? 1 : 3;
    const dim3 Gw1(CH / 128, 8), Gw2(CH / 128, 2);   // x = row tiles
    for (int tt = 0; tt < nOuter; ++tt) {
      const long r0 = (long)tt * N3;            // 0 in full mode
      const long TO = full ? 0 : (long)tt;      // per-type pre-offset multiplier
      const long EN = full ? 1 : 0;             // in-kernel per-type stride enable
      const float* xC   = agent_x + r0 * 256;
      float*       outC = outp + r0 * 256;

      // ---- self branch ----
      cast_k<<<CH / 4, B256, 0, stream>>>(xC, xbf);
      gemm_k<EPI_RELU_BIAS><<<Gw2, B256, 0, stream>>>(
          xbf, 256, wT + SELF_WT + TO * 65536, 256, EN * 65536,
          self_b + TO * 256, EN * 256, nullptr, bbuf, 256, nullptr, nullptr, 256, 256);
      gemm_k<EPI_ACC_INIT><<<Gw2, B256, 0, stream>>>(
          bbuf, 256, wT + OUT_WT + TO * 262144 + 0 * 256, 1024, EN * 262144,
          out_b + TO * 256, EN * 256, outF32, nullptr, 0, nullptr, nullptr, 256, 256);

      // ---- l2a branch ----
      ln_cat3_k<<<CH / 4, B256, 0, stream>>>(lane_x, xC, l2a_src + r0,
                                             l2a_ln_s, l2a_ln_b, nbuf);
      gemm_k<EPI_RELU_BIAS><<<Gw1, B256, 0, stream>>>(
          nbuf, 768, wT + L2A_W1T, 768, 0, l2a_b1, 0, nullptr, h1, 1024, nullptr, nullptr, 768, 1024);
      gemm_k<EPI_BIAS><<<Gw2, B256, 0, stream>>>(
          h1, 1024, wT + L2A_W2T, 1024, 0, l2a_b2, 0, nullptr, bbuf, 256, nullptr, nullptr, 1024, 256);
      gemm_k<EPI_ACC_ADD><<<Gw2, B256, 0, stream>>>(
          bbuf, 256, wT + OUT_WT + TO * 262144 + 1 * 256, 1024, EN * 262144,
          nullptr, 0, outF32, nullptr, 0, nullptr, nullptr, 256, 256);

      // ---- g2a branch ----
      ln_cat2_k<<<CH / 4, B256, 0, stream>>>(poly_x, xC, g2a_src + r0,
                                             g2a_ln_s, g2a_ln_b, nbuf);
      gemm_k<EPI_RELU_BIAS><<<Gw1, B256, 0, stream>>>(
          nbuf, 512, wT + G2A_W1T, 512, 0, g2a_b1, 0, nullptr, h1, 1024, nullptr, nullptr, 512, 1024);
      gemm_k<EPI_BIAS><<<Gw2, B256, 0, stream>>>(
          h1, 1024, wT + G2A_W2T, 1024, 0, g2a_b2, 0, nullptr, bbuf, 256, nullptr, nullptr, 1024, 256);
      gemm_k<EPI_ACC_ADD><<<Gw2, B256, 0, stream>>>(
          bbuf, 256, wT + OUT_WT + TO * 262144 + 2 * 256, 1024, EN * 262144,
          nullptr, 0, outF32, nullptr, 0, nullptr, nullptr, 256, 256);

      // ---- other branch: per src type s ----
      for (int s = 0; s < 3; ++s) {
        ln_cat3_k<<<CH / 4, B256, 0, stream>>>(
            agent_x, xC, other_src + (long)s * N_AG + r0,
            oth_ln_s + s * 768, oth_ln_b + s * 768, nbuf);
        gemm_k<EPI_RELU_BIAS><<<Gw1, B256, 0, stream>>>(
            nbuf, 768, wT + OTH_W1T + (long)s * 786432, 768, 0,
            oth_b1 + s * 1024, 0, nullptr, h1, 1024, nullptr, nullptr, 768, 1024);
        gemm_k<EPI_BIAS><<<Gw2, B256, 0, stream>>>(
            h1, 1024, wT + OTH_W2T + (long)s * 262144, 1024, 0,
            oth_b2 + s * 256, 0, nullptr, bbuf, 256, nullptr, nullptr, 1024, 256);
        gemm_k<EPI_ACC_ADD><<<Gw2, B256, 0, stream>>>(
            bbuf, 256, wT + OUT_WT + TO * 262144 + 3 * 256, 1024, EN * 262144,
            nullptr, 0, outF32, nullptr, 0, nullptr, nullptr, 256, 256);
      }

      // ---- FFN ----
      ln_ffn_k<<<CH / 4, B256, 0, stream>>>(outF32, ffn_ln_s + TO * 256,
                                            ffn_ln_b + TO * 256, ybuf, EN * 256);
      gemm_k<EPI_BIAS><<<Gw1, B256, 0, stream>>>(
          ybuf, 256, wT + FFN_W1T + TO * 262144, 256, EN * 262144,
          ffn_b1 + TO * 1024, EN * 1024, nullptr, g_pre, 1024, nullptr, nullptr, 256, 1024);
      gemm_k<EPI_BIAS><<<Gw1, B256, 0, stream>>>(
          ybuf, 256, wT + FFN_W3T + TO * 262144, 256, EN * 262144,
          ffn_b3 + TO * 1024, EN * 1024, nullptr, u_pre, 1024, nullptr, nullptr, 256, 1024);
      silu_mul_k<<<CH, B256, 0, stream>>>(g_pre, u_pre);
      gemm_k<EPI_FINAL><<<Gw2, B256, 0, stream>>>(
          g_pre, 1024, wT + FFN_W2T + TO * 262144, 1024, EN * 262144,
          ffn_b2 + TO * 256, EN * 256, outF32, nullptr, 256, xC, outC, 1024, 256);
    }
    return;
  }

  if (ws_size < TIER_C) {
    fill_k<<<(out_size + 255) / 256, B256, 0, stream>>>(outp, out_size);
    return;
  }

  // ================= Tier C: chunked path (11.5 MiB) =================
  const int CH = 2048;
  char* base = (char*)d_ws;
  bf16*  wt     = (bf16*)base;
  bf16*  nbuf   = (bf16*)(base + 1572864L);
  bf16*  bbuf   = (bf16*)(base + 4718592L);
  bf16*  h1     = (bf16*)(base + 5767168L);
  float* outF32 = (float*)(base + 9961472L);
  bf16*  ybuf   = (bf16*)(base + 524288L);
  bf16*  xbf    = h1;
  bf16*  g_pre  = h1;
  bf16*  u_pre  = nbuf;

  const dim3 Gw1(CH / 128, 8), Gw2(CH / 128, 2);
  auto TR = [&](const float* s, int K, int Nc) {
    transpose_k<<<dim3(Nc / 32, K / 32), B256, 0, stream>>>(s, wt, K, Nc, 0, 0);
  };

  for (int t = 0; t < 3; ++t) {
    for (int c = 0; c < N3 / CH; ++c) {
      const long r0 = (long)t * N3 + (long)c * CH;
      const float* xC   = agent_x + r0 * 256;
      float*       outC = outp + r0 * 256;

      cast_k<<<CH / 4, B256, 0, stream>>>(xC, xbf);
      TR(self_W + (long)t * 65536, 256, 256);
      gemm_k<EPI_RELU_BIAS><<<Gw2, B256, 0, stream>>>(
          xbf, 256, wt, 256, 0, self_b + t * 256, 0, nullptr, bbuf, 256, nullptr, nullptr, 256, 256);
      TR(out_W + (long)t * 262144 + 0 * 65536, 256, 256);
      gemm_k<EPI_ACC_INIT><<<Gw2, B256, 0, stream>>>(
          bbuf, 256, wt, 256, 0, out_b + t * 256, 0, outF32, nullptr, 0, nullptr, nullptr, 256, 256);

      ln_cat3_k<<<CH / 4, B256, 0, stream>>>(lane_x, xC, l2a_src + r0,
                                             l2a_ln_s, l2a_ln_b, nbuf);
      TR(l2a_w1, 768, 1024);
      gemm_k<EPI_RELU_BIAS><<<Gw1, B256, 0, stream>>>(
          nbuf, 768, wt, 768, 0, l2a_b1, 0, nullptr, h1, 1024, nullptr, nullptr, 768, 1024);
      TR(l2a_w2, 1024, 256);
      gemm_k<EPI_BIAS><<<Gw2, B256, 0, stream>>>(
          h1, 1024, wt, 1024, 0, l2a_b2, 0, nullptr, bbuf, 256, nullptr, nullptr, 1024, 256);
      TR(out_W + (long)t * 262144 + 1 * 65536, 256, 256);
      gemm_k<EPI_ACC_ADD><<<Gw2, B256, 0, stream>>>(
          bbuf, 256, wt, 256, 0, nullptr, 0, outF32, nullptr, 0, nullptr, nullptr, 256, 256);

      ln_cat2_k<<<CH / 4, B256, 0, stream>>>(poly_x, xC, g2a_src + r0,
                                             g2a_ln_s, g2a_ln_b, nbuf);
      TR(g2a_w1, 512, 1024);
      gemm_k<EPI_RELU_BIAS><<<Gw1, B256, 0, stream>>>(
          nbuf, 512, wt, 512, 0, g2a_b1, 0, nullptr, h1, 1024, nullptr, nullptr, 512, 1024);
      TR(g2a_w2, 1024, 256);
      gemm_k<EPI_BIAS><<<Gw2, B256, 0, stream>>>(
          h1, 1024, wt, 1024, 0, g2a_b2, 0, nullptr, bbuf, 256, nullptr, nullptr, 1024, 256);
      TR(out_W + (long)t * 262144 + 2 * 65536, 256, 256);
      gemm_k<EPI_ACC_ADD><<<Gw2, B256, 0, stream>>>(
          bbuf, 256, wt, 256, 0, nullptr, 0, outF32, nullptr, 0, nullptr, nullptr, 256, 256);

      for (int s = 0; s < 3; ++s) {
        ln_cat3_k<<<CH / 4, B256, 0, stream>>>(
            agent_x, xC, other_src + (long)s * N_AG + r0,
            oth_ln_s + s * 768, oth_ln_b + s * 768, nbuf);
        TR(oth_w1 + (long)s * 786432, 768, 1024);
        gemm_k<EPI_RELU_BIAS><<<Gw1, B256, 0, stream>>>(
            nbuf, 768, wt, 768, 0, oth_b1 + s * 1024, 0, nullptr, h1, 1024, nullptr, nullptr, 768, 1024);
        TR(oth_w2 + (long)s * 262144, 1024, 256);
        gemm_k<EPI_BIAS><<<Gw2, B256, 0, stream>>>(
            h1, 1024, wt, 1024, 0, oth_b2 + s * 256, 0, nullptr, bbuf, 256, nullptr, nullptr, 1024, 256);
        TR(out_W + (long)t * 262144 + 3 * 65536, 256, 256);
        gemm_k<EPI_ACC_ADD><<<Gw2, B256, 0, stream>>>(
            bbuf, 256, wt, 256, 0, nullptr, 0, outF32, nullptr, 0, nullptr, nullptr, 256, 256);
      }

      ln_ffn_k<<<CH / 4, B256, 0, stream>>>(outF32, ffn_ln_s + t * 256,
                                            ffn_ln_b + t * 256, ybuf, 0);
      TR(ffn_w1 + (long)t * 262144, 256, 1024);
      gemm_k<EPI_BIAS><<<Gw1, B256, 0, stream>>>(
          ybuf, 256, wt, 256, 0, ffn_b1 + t * 1024, 0, nullptr, g_pre, 1024, nullptr, nullptr, 256, 1024);
      TR(ffn_w3 + (long)t * 262144, 256, 1024);
      gemm_k<EPI_BIAS><<<Gw1, B256, 0, stream>>>(
          ybuf, 256, wt, 256, 0, ffn_b3 + t * 1024, 0, nullptr, u_pre, 1024, nullptr, nullptr, 256, 1024);
      silu_mul_k<<<CH, B256, 0, stream>>>(g_pre, u_pre);
      TR(ffn_w2 + (long)t * 262144, 1024, 256);
      gemm_k<EPI_FINAL><<<Gw2, B256, 0, stream>>>(
          g_pre, 1024, wt, 1024, 0, ffn_b2 + t * 256, 0, outF32, nullptr, 256, xC, outC, 1024, 256);
    }
  }
}

// Round 8
// 1016.339 us; speedup vs baseline: 1.1684x; 1.1684x over previous
//
#include <hip/hip_runtime.h>
#include <hip/hip_bf16.h>

typedef __hip_bfloat16 bf16;
typedef __bf16 v8bf __attribute__((ext_vector_type(8)));
typedef float f32x4 __attribute__((ext_vector_type(4)));

#define N_AG 24576
#define N3 8192

struct __align__(8) bf4 { bf16 x, y, z, w; };
__device__ __forceinline__ bf4 mk4(float a, float b, float c, float d) {
  bf4 r{__float2bfloat16(a), __float2bfloat16(b), __float2bfloat16(c), __float2bfloat16(d)};
  return r;
}

// ---------------- epilogue modes ----------------
enum {
  EPI_RELU_BIAS = 0,  // Cout(bf16) = relu(v + bias)
  EPI_BIAS      = 1,  // Cout(bf16) = v + bias
  EPI_ACC_INIT  = 2,  // accbuf(f32) = v + bias
  EPI_ACC_ADD   = 3,  // accbuf(f32) += v + bias
  EPI_FINAL     = 4   // CoutF(f32) = accbuf + v + bias + resid
};

// async 16B/lane global->LDS DMA; LDS dest = wave-uniform base + lane*16
__device__ __forceinline__ void gl_lds16(const bf16* g, short* l) {
  __builtin_amdgcn_global_load_lds(
      (const __attribute__((address_space(1))) unsigned int*)g,
      (__attribute__((address_space(3))) unsigned int*)l, 16, 0, 0);
}

// ---------------- GEMM: C[M,Nc] = A[M,K] @ B[K,Nc], B given transposed ----------------
// A, Bt bf16; bias/acc/resid/final f32. 128x128 tile, BK=32, 4 waves, 4x4
// mfma_f32_16x16x32_bf16 (C/D: col=lane&15, row=quad*4+reg).
// LDS: row-major [128 rows][4 x 16B chunks] with XOR swizzle: physical chunk
// of logical k-chunk c for row r is c ^ s(r), s(r) = (r&3)^((r>>2)&1).
//  - staging (DMA dest = base+lane*16): lane i covers (row i>>2, phys chunk
//    i&3) so it FETCHES global chunk (i&3)^s(row); the 4 lanes of one row
//    still read the same contiguous 64B segment -> R6-level coalescing.
//  - frag read: ds_read_b128 at chunk quad^s(row); 16 lanes cover all 8
//    16B bank-groups twice -> 2-way = conflict-free (m136).
// Grid: x = row tiles (multiple of 8 -> col tiles of one row share an XCD).
template<int EPI>
__global__ __launch_bounds__(256)
void gemm_k(const bf16* __restrict__ A, int lda,
            const bf16* __restrict__ Bt, int ldb, long bTs,
            const float* __restrict__ bias, long biasTs,
            float* __restrict__ accbuf,
            bf16* __restrict__ Cout, int ldc,
            const float* __restrict__ resid,
            float* __restrict__ CoutF,
            int K, int Nc)
{
  __shared__ __align__(16) short As[128 * 32];
  __shared__ __align__(16) short Bs[128 * 32];

  const int tid  = threadIdx.x;
  const int lane = tid & 63;
  const int w    = tid >> 6;
  const int quad = lane >> 4;
  const int l15  = lane & 15;
  const int row0 = blockIdx.x * 128;
  const int col0 = blockIdx.y * 128;
  const int t    = row0 >> 13;

  const bf16*  Bp = Bt + (long)t * bTs;
  const float* bp = bias ? bias + (long)t * biasTs : nullptr;

  f32x4 acc[4][4];
  const f32x4 zero = {0.f, 0.f, 0.f, 0.f};
#pragma unroll
  for (int i = 0; i < 4; ++i)
#pragma unroll
    for (int j = 0; j < 4; ++j) acc[i][j] = zero;

  // staging: wave w rows [w*32, w*32+32); lane i -> (row i>>2, phys chunk i&3)
  const int srow = (w << 5) + (lane >> 2);
  const int ss   = ((lane >> 2) & 3) ^ ((lane >> 4) & 1);   // s(srow), same for srow+16
  const int sc   = ((lane & 3) ^ ss) << 3;                  // global elem offset fetched
  const bf16* aG = A  + (long)(row0 + srow) * lda + sc;
  const bf16* bG = Bp + (long)(col0 + srow) * ldb + sc;
  short* AsW = As + w * 1024;      // wave-uniform LDS base (32 rows * 32 shorts)
  short* BsW = Bs + w * 1024;

  const int wr = (w >> 1) * 64;
  const int wc = (w & 1) * 64;

  // frag-read swizzle (row low bits = l15 for all frag rows)
  const int fs = (l15 & 3) ^ ((l15 >> 2) & 1);
  const int fchunk = ((0 ^ fs)) * 8;   // base for quad^fs computed per quad below

  for (int k0 = 0; k0 < K; k0 += 32) {
    gl_lds16(aG + k0,                  AsW);
    gl_lds16(aG + k0 + (long)16 * lda, AsW + 512);
    gl_lds16(bG + k0,                  BsW);
    gl_lds16(bG + k0 + (long)16 * ldb, BsW + 512);
    __syncthreads();

    const int pc = (quad ^ fs) * 8;   // physical chunk elem offset
    v8bf af[4], bfm[4];
#pragma unroll
    for (int i = 0; i < 4; ++i) {
      af[i]  = *(const v8bf*)&As[(wr + i * 16 + l15) * 32 + pc];
      bfm[i] = *(const v8bf*)&Bs[(wc + i * 16 + l15) * 32 + pc];
    }
#pragma unroll
    for (int i = 0; i < 4; ++i)
#pragma unroll
      for (int j = 0; j < 4; ++j)
        acc[i][j] = __builtin_amdgcn_mfma_f32_16x16x32_bf16(af[i], bfm[j], acc[i][j], 0, 0, 0);
    __syncthreads();
  }
  (void)fchunk;

#pragma unroll
  for (int ct = 0; ct < 4; ++ct) {
    const int col = col0 + wc + ct * 16 + l15;
    const float bv = bp ? bp[col] : 0.f;
#pragma unroll
    for (int rt = 0; rt < 4; ++rt) {
#pragma unroll
      for (int i = 0; i < 4; ++i) {
        const int row = row0 + wr + rt * 16 + quad * 4 + i;
        float v = acc[rt][ct][i] + bv;
        if constexpr (EPI == EPI_RELU_BIAS) {
          Cout[(long)row * ldc + col] = __float2bfloat16(v > 0.f ? v : 0.f);
        } else if constexpr (EPI == EPI_BIAS) {
          Cout[(long)row * ldc + col] = __float2bfloat16(v);
        } else if constexpr (EPI == EPI_ACC_INIT) {
          accbuf[(long)row * Nc + col] = v;
        } else if constexpr (EPI == EPI_ACC_ADD) {
          accbuf[(long)row * Nc + col] += v;
        } else {  // EPI_FINAL
          CoutF[(long)row * ldc + col] =
              accbuf[(long)row * Nc + col] + v + resid[(long)row * ldc + col];
        }
      }
    }
  }
}

// ---------------- weight transpose+cast: src f32 [K,Nc] -> dst bf16 [Nc,K], batched z ----------------
__global__ __launch_bounds__(256)
void transpose_k(const float* __restrict__ src, bf16* __restrict__ dst,
                 int K, int Nc, long sB, long dB)
{
  __shared__ bf16 tile[32][33];
  const int b = blockIdx.z;
  const float* s = src + (long)b * sB;
  bf16* d = dst + (long)b * dB;
  const int kb = blockIdx.y * 32, nb = blockIdx.x * 32;
  const int tx = threadIdx.x & 31, ty = threadIdx.x >> 5;
#pragma unroll
  for (int i = 0; i < 32; i += 8)
    tile[ty + i][tx] = __float2bfloat16(s[(long)(kb + ty + i) * Nc + nb + tx]);
  __syncthreads();
#pragma unroll
  for (int i = 0; i < 32; i += 8)
    d[(long)(nb + ty + i) * K + kb + tx] = tile[tx][ty + i];
}

// ---------------- f32 -> bf16 cast, 4 elems/thread ----------------
__global__ __launch_bounds__(256)
void cast_k(const float* __restrict__ src, bf16* __restrict__ dst)
{
  const long i = (long)blockIdx.x * 256 + threadIdx.x;
  const float4 v = ((const float4*)src)[i];
  ((bf4*)dst)[i] = mk4(v.x, v.y, v.z, v.w);
}

// ---------------- wave-wide reduce (all lanes get totals) ----------------
__device__ __forceinline__ void wave_reduce2(float& s, float& q) {
#pragma unroll
  for (int off = 32; off > 0; off >>= 1) {
    s += __shfl_xor(s, off, 64);
    q += __shfl_xor(q, off, 64);
  }
}

// ---------------- LN over concat([f, x, f]) width 768; one wave per row ----------------
__global__ __launch_bounds__(256)
void ln_cat3_k(const float* __restrict__ feat, const float* __restrict__ x,
               const int* __restrict__ srcIdx,
               const float* __restrict__ ls, const float* __restrict__ lb,
               bf16* __restrict__ out)
{
  const int w = threadIdx.x >> 6, lane = threadIdx.x & 63;
  const int r = blockIdx.x * 4 + w;
  const int src = srcIdx[r];
  const float4 f4 = ((const float4*)(feat + (long)src * 256))[lane];
  const float4 x4 = ((const float4*)(x + (long)r * 256))[lane];
  float s = 2.f * (f4.x + f4.y + f4.z + f4.w) + (x4.x + x4.y + x4.z + x4.w);
  float q = 2.f * (f4.x * f4.x + f4.y * f4.y + f4.z * f4.z + f4.w * f4.w) +
            (x4.x * x4.x + x4.y * x4.y + x4.z * x4.z + x4.w * x4.w);
  wave_reduce2(s, q);
  const float mu  = s * (1.f / 768.f);
  const float var = q * (1.f / 768.f) - mu * mu;
  const float inv = rsqrtf(var + 1e-5f);
  const float4 s0 = ((const float4*)ls)[lane],        b0 = ((const float4*)lb)[lane];
  const float4 s1 = ((const float4*)(ls + 256))[lane], b1 = ((const float4*)(lb + 256))[lane];
  const float4 s2 = ((const float4*)(ls + 512))[lane], b2 = ((const float4*)(lb + 512))[lane];
  bf4* o = (bf4*)(out + (long)r * 768);
  o[lane] = mk4((f4.x - mu) * inv * s0.x + b0.x, (f4.y - mu) * inv * s0.y + b0.y,
                (f4.z - mu) * inv * s0.z + b0.z, (f4.w - mu) * inv * s0.w + b0.w);
  o[64 + lane] = mk4((x4.x - mu) * inv * s1.x + b1.x, (x4.y - mu) * inv * s1.y + b1.y,
                     (x4.z - mu) * inv * s1.z + b1.z, (x4.w - mu) * inv * s1.w + b1.w);
  o[128 + lane] = mk4((f4.x - mu) * inv * s2.x + b2.x, (f4.y - mu) * inv * s2.y + b2.y,
                      (f4.z - mu) * inv * s2.z + b2.z, (f4.w - mu) * inv * s2.w + b2.w);
}

// ---------------- LN over concat([f, x]) width 512; one wave per row ----------------
__global__ __launch_bounds__(256)
void ln_cat2_k(const float* __restrict__ feat, const float* __restrict__ x,
               const int* __restrict__ srcIdx,
               const float* __restrict__ ls, const float* __restrict__ lb,
               bf16* __restrict__ out)
{
  const int w = threadIdx.x >> 6, lane = threadIdx.x & 63;
  const int r = blockIdx.x * 4 + w;
  const int src = srcIdx[r];
  const float4 f4 = ((const float4*)(feat + (long)src * 256))[lane];
  const float4 x4 = ((const float4*)(x + (long)r * 256))[lane];
  float s = (f4.x + f4.y + f4.z + f4.w) + (x4.x + x4.y + x4.z + x4.w);
  float q = (f4.x * f4.x + f4.y * f4.y + f4.z * f4.z + f4.w * f4.w) +
            (x4.x * x4.x + x4.y * x4.y + x4.z * x4.z + x4.w * x4.w);
  wave_reduce2(s, q);
  const float mu  = s * (1.f / 512.f);
  const float var = q * (1.f / 512.f) - mu * mu;
  const float inv = rsqrtf(var + 1e-5f);
  const float4 s0 = ((const float4*)ls)[lane],        b0 = ((const float4*)lb)[lane];
  const float4 s1 = ((const float4*)(ls + 256))[lane], b1 = ((const float4*)(lb + 256))[lane];
  bf4* o = (bf4*)(out + (long)r * 512);
  o[lane] = mk4((f4.x - mu) * inv * s0.x + b0.x, (f4.y - mu) * inv * s0.y + b0.y,
                (f4.z - mu) * inv * s0.z + b0.z, (f4.w - mu) * inv * s0.w + b0.w);
  o[64 + lane] = mk4((x4.x - mu) * inv * s1.x + b1.x, (x4.y - mu) * inv * s1.y + b1.y,
                     (x4.z - mu) * inv * s1.z + b1.z, (x4.w - mu) * inv * s1.w + b1.w);
}

// ---------------- FFN layernorm width 256: f32 in, bf16 out; one wave per row ----------------
__global__ __launch_bounds__(256)
void ln_ffn_k(const float* __restrict__ ob, const float* __restrict__ ls,
              const float* __restrict__ lb, bf16* __restrict__ y, long lsStride)
{
  const int w = threadIdx.x >> 6, lane = threadIdx.x & 63;
  const int r = blockIdx.x * 4 + w;
  const long po = (long)(r >> 13) * lsStride;
  const float4 v4 = ((const float4*)(ob + (long)r * 256))[lane];
  float s = v4.x + v4.y + v4.z + v4.w;
  float q = v4.x * v4.x + v4.y * v4.y + v4.z * v4.z + v4.w * v4.w;
  wave_reduce2(s, q);
  const float mu  = s * (1.f / 256.f);
  const float var = q * (1.f / 256.f) - mu * mu;
  const float inv = rsqrtf(var + 1e-5f);
  const float4 s0 = ((const float4*)(ls + po))[lane];
  const float4 b0 = ((const float4*)(lb + po))[lane];
  ((bf4*)(y + (long)r * 256))[lane] =
      mk4((v4.x - mu) * inv * s0.x + b0.x, (v4.y - mu) * inv * s0.y + b0.y,
          (v4.z - mu) * inv * s0.z + b0.z, (v4.w - mu) * inv * s0.w + b0.w);
}

// ---------------- g = silu(g) * u, 4 elems/thread ----------------
__global__ __launch_bounds__(256)
void silu_mul_k(bf16* __restrict__ g, const bf16* __restrict__ u)
{
  const long i = (long)blockIdx.x * 256 + threadIdx.x;
  const bf4 g4 = ((const bf4*)g)[i];
  const bf4 u4 = ((const bf4*)u)[i];
  float a = __bfloat162float(g4.x), b = __bfloat162float(g4.y);
  float c = __bfloat162float(g4.z), d = __bfloat162float(g4.w);
  a = a / (1.f + expf(-a)) * __bfloat162float(u4.x);
  b = b / (1.f + expf(-b)) * __bfloat162float(u4.y);
  c = c / (1.f + expf(-c)) * __bfloat162float(u4.z);
  d = d / (1.f + expf(-d)) * __bfloat162float(u4.w);
  ((bf4*)g)[i] = mk4(a, b, c, d);
}

// ---------------- sentinel fill (diagnostic) ----------------
__global__ __launch_bounds__(256)
void fill_k(float* __restrict__ p, int n)
{
  const int i = blockIdx.x * 256 + threadIdx.x;
  if (i < n) p[i] = 2.0f;
}

// ---------------- host ----------------
extern "C" void kernel_launch(void* const* d_in, const int* in_sizes, int n_in,
                              void* d_out, int out_size, void* d_ws, size_t ws_size,
                              hipStream_t stream)
{
  const float* agent_x  = (const float*)d_in[0];
  const float* lane_x   = (const float*)d_in[1];
  const float* poly_x   = (const float*)d_in[2];
  const int*   l2a_src  = (const int*)d_in[3];
  const int*   g2a_src  = (const int*)d_in[4];
  const int*   other_src= (const int*)d_in[5];
  const float* self_W   = (const float*)d_in[6];
  const float* self_b   = (const float*)d_in[7];
  const float* out_W    = (const float*)d_in[8];
  const float* out_b    = (const float*)d_in[9];
  const float* ffn_ln_s = (const float*)d_in[10];
  const float* ffn_ln_b = (const float*)d_in[11];
  const float* ffn_w1   = (const float*)d_in[12];
  const float* ffn_b1   = (const float*)d_in[13];
  const float* ffn_w2   = (const float*)d_in[14];
  const float* ffn_b2   = (const float*)d_in[15];
  const float* ffn_w3   = (const float*)d_in[16];
  const float* ffn_b3   = (const float*)d_in[17];
  const float* l2a_ln_s = (const float*)d_in[18];
  const float* l2a_ln_b = (const float*)d_in[19];
  const float* l2a_w1   = (const float*)d_in[20];
  const float* l2a_b1   = (const float*)d_in[21];
  const float* l2a_w2   = (const float*)d_in[22];
  const float* l2a_b2   = (const float*)d_in[23];
  const float* g2a_ln_s = (const float*)d_in[24];
  const float* g2a_ln_b = (const float*)d_in[25];
  const float* g2a_w1   = (const float*)d_in[26];
  const float* g2a_b1   = (const float*)d_in[27];
  const float* g2a_w2   = (const float*)d_in[28];
  const float* g2a_b2   = (const float*)d_in[29];
  const float* oth_ln_s = (const float*)d_in[30];
  const float* oth_ln_b = (const float*)d_in[31];
  const float* oth_w1   = (const float*)d_in[32];
  const float* oth_b1   = (const float*)d_in[33];
  const float* oth_w2   = (const float*)d_in[34];
  const float* oth_b2   = (const float*)d_in[35];

  float* outp = (float*)d_out;
  const dim3 B256(256);

  // W^T element offsets within the hoisted wT block (8,323,072 elems = 16,646,144 B)
  const long SELF_WT = 0,        L2A_W1T = 196608,  L2A_W2T = 983040;
  const long G2A_W1T = 1245184,  G2A_W2T = 1769472;
  const long OTH_W1T = 2031616,  OTH_W2T = 4390912, OUT_WT = 5177344;
  const long FFN_W1T = 5963776,  FFN_W3T = 6750208, FFN_W2T = 7536640;

  const size_t TIER_A = 155058176;  // full-N hoisted (PROVEN: fired R5-R7)
  const size_t TIER_B = 62783488;   // per-type hoisted
  const size_t TIER_C = 12058624;   // chunked, per-stage transposes

  if (ws_size >= TIER_B) {
    // ================= hoisted tiers (A: full-N, B: per-type) =================
    const bool full = ws_size >= TIER_A;
    const int  CH   = full ? N_AG : N3;
    char* base = (char*)d_ws;
    bf16*  wT     = (bf16*)base;
    bf16*  nbuf   = (bf16*)(base + 16646144L);
    bf16*  bbuf   = (bf16*)(base + 16646144L + (long)CH * 1536);
    bf16*  h1     = (bf16*)(base + 16646144L + (long)CH * 2048);
    float* outF32 = (float*)(base + 16646144L + (long)CH * 4096);
    bf16*  ybuf   = (bf16*)(base + 16646144L + (long)CH * 5120);
    bf16*  xbf    = h1;     // bf16 cast of chunk agent rows (dead before h1 written)
    bf16*  g_pre  = h1;
    bf16*  u_pre  = nbuf;   // nbuf+bbuf contiguous = CH x 1024 bf16

    // ---- transpose all weights once ----
    auto TRB = [&](const float* s, long dOff, int K, int Nc, long sB, long dB, int b) {
      transpose_k<<<dim3(Nc / 32, K / 32, b), B256, 0, stream>>>(s, wT + dOff, K, Nc, sB, dB);
    };
    TRB(self_W, SELF_WT, 256, 256,  65536, 65536, 3);
    TRB(l2a_w1, L2A_W1T, 768, 1024, 0, 0, 1);
    TRB(l2a_w2, L2A_W2T, 1024, 256, 0, 0, 1);
    TRB(g2a_w1, G2A_W1T, 512, 1024, 0, 0, 1);
    TRB(g2a_w2, G2A_W2T, 1024, 256, 0, 0, 1);
    TRB(oth_w1, OTH_W1T, 768, 1024, 786432, 786432, 3);
    TRB(oth_w2, OTH_W2T, 1024, 256, 262144, 262144, 3);
    TRB(out_W,  OUT_WT,  1024, 256, 262144, 262144, 3);
    TRB(ffn_w1, FFN_W1T, 256, 1024, 262144, 262144, 3);
    TRB(ffn_w3, FFN_W3T, 256, 1024, 262144, 262144, 3);
    TRB(ffn_w2, FFN_W2T, 1024, 256, 262144, 262144, 3);

    const int nOuter = full ? 1 : 3;
    const dim3 Gw1(CH / 128, 8), Gw2(CH / 128, 2);   // x = row tiles
    for (int tt = 0; tt < nOuter; ++tt) {
      const long r0 = (long)tt * N3;            // 0 in full mode
      const long TO = full ? 0 : (long)tt;      // per-type pre-offset multiplier
      const long EN = full ? 1 : 0;             // in-kernel per-type stride enable
      const float* xC   = agent_x + r0 * 256;
      float*       outC = outp + r0 * 256;

      // ---- self branch ----
      cast_k<<<CH / 4, B256, 0, stream>>>(xC, xbf);
      gemm_k<EPI_RELU_BIAS><<<Gw2, B256, 0, stream>>>(
          xbf, 256, wT + SELF_WT + TO * 65536, 256, EN * 65536,
          self_b + TO * 256, EN * 256, nullptr, bbuf, 256, nullptr, nullptr, 256, 256);
      gemm_k<EPI_ACC_INIT><<<Gw2, B256, 0, stream>>>(
          bbuf, 256, wT + OUT_WT + TO * 262144 + 0 * 256, 1024, EN * 262144,
          out_b + TO * 256, EN * 256, outF32, nullptr, 0, nullptr, nullptr, 256, 256);

      // ---- l2a branch ----
      ln_cat3_k<<<CH / 4, B256, 0, stream>>>(lane_x, xC, l2a_src + r0,
                                             l2a_ln_s, l2a_ln_b, nbuf);
      gemm_k<EPI_RELU_BIAS><<<Gw1, B256, 0, stream>>>(
          nbuf, 768, wT + L2A_W1T, 768, 0, l2a_b1, 0, nullptr, h1, 1024, nullptr, nullptr, 768, 1024);
      gemm_k<EPI_BIAS><<<Gw2, B256, 0, stream>>>(
          h1, 1024, wT + L2A_W2T, 1024, 0, l2a_b2, 0, nullptr, bbuf, 256, nullptr, nullptr, 1024, 256);
      gemm_k<EPI_ACC_ADD><<<Gw2, B256, 0, stream>>>(
          bbuf, 256, wT + OUT_WT + TO * 262144 + 1 * 256, 1024, EN * 262144,
          nullptr, 0, outF32, nullptr, 0, nullptr, nullptr, 256, 256);

      // ---- g2a branch ----
      ln_cat2_k<<<CH / 4, B256, 0, stream>>>(poly_x, xC, g2a_src + r0,
                                             g2a_ln_s, g2a_ln_b, nbuf);
      gemm_k<EPI_RELU_BIAS><<<Gw1, B256, 0, stream>>>(
          nbuf, 512, wT + G2A_W1T, 512, 0, g2a_b1, 0, nullptr, h1, 1024, nullptr, nullptr, 512, 1024);
      gemm_k<EPI_BIAS><<<Gw2, B256, 0, stream>>>(
          h1, 1024, wT + G2A_W2T, 1024, 0, g2a_b2, 0, nullptr, bbuf, 256, nullptr, nullptr, 1024, 256);
      gemm_k<EPI_ACC_ADD><<<Gw2, B256, 0, stream>>>(
          bbuf, 256, wT + OUT_WT + TO * 262144 + 2 * 256, 1024, EN * 262144,
          nullptr, 0, outF32, nullptr, 0, nullptr, nullptr, 256, 256);

      // ---- other branch: per src type s ----
      for (int s = 0; s < 3; ++s) {
        ln_cat3_k<<<CH / 4, B256, 0, stream>>>(
            agent_x, xC, other_src + (long)s * N_AG + r0,
            oth_ln_s + s * 768, oth_ln_b + s * 768, nbuf);
        gemm_k<EPI_RELU_BIAS><<<Gw1, B256, 0, stream>>>(
            nbuf, 768, wT + OTH_W1T + (long)s * 786432, 768, 0,
            oth_b1 + s * 1024, 0, nullptr, h1, 1024, nullptr, nullptr, 768, 1024);
        gemm_k<EPI_BIAS><<<Gw2, B256, 0, stream>>>(
            h1, 1024, wT + OTH_W2T + (long)s * 262144, 1024, 0,
            oth_b2 + s * 256, 0, nullptr, bbuf, 256, nullptr, nullptr, 1024, 256);
        gemm_k<EPI_ACC_ADD><<<Gw2, B256, 0, stream>>>(
            bbuf, 256, wT + OUT_WT + TO * 262144 + 3 * 256, 1024, EN * 262144,
            nullptr, 0, outF32, nullptr, 0, nullptr, nullptr, 256, 256);
      }

      // ---- FFN ----
      ln_ffn_k<<<CH / 4, B256, 0, stream>>>(outF32, ffn_ln_s + TO * 256,
                                            ffn_ln_b + TO * 256, ybuf, EN * 256);
      gemm_k<EPI_BIAS><<<Gw1, B256, 0, stream>>>(
          ybuf, 256, wT + FFN_W1T + TO * 262144, 256, EN * 262144,
          ffn_b1 + TO * 1024, EN * 1024, nullptr, g_pre, 1024, nullptr, nullptr, 256, 1024);
      gemm_k<EPI_BIAS><<<Gw1, B256, 0, stream>>>(
          ybuf, 256, wT + FFN_W3T + TO * 262144, 256, EN * 262144,
          ffn_b3 + TO * 1024, EN * 1024, nullptr, u_pre, 1024, nullptr, nullptr, 256, 1024);
      silu_mul_k<<<CH, B256, 0, stream>>>(g_pre, u_pre);
      gemm_k<EPI_FINAL><<<Gw2, B256, 0, stream>>>(
          g_pre, 1024, wT + FFN_W2T + TO * 262144, 1024, EN * 262144,
          ffn_b2 + TO * 256, EN * 256, outF32, nullptr, 256, xC, outC, 1024, 256);
    }
    return;
  }

  if (ws_size < TIER_C) {
    fill_k<<<(out_size + 255) / 256, B256, 0, stream>>>(outp, out_size);
    return;
  }

  // ================= Tier C: chunked path (11.5 MiB) =================
  const int CH = 2048;
  char* base = (char*)d_ws;
  bf16*  wt     = (bf16*)base;
  bf16*  nbuf   = (bf16*)(base + 1572864L);
  bf16*  bbuf   = (bf16*)(base + 4718592L);
  bf16*  h1     = (bf16*)(base + 5767168L);
  float* outF32 = (float*)(base + 9961472L);
  bf16*  ybuf   = (bf16*)(base + 524288L);
  bf16*  xbf    = h1;
  bf16*  g_pre  = h1;
  bf16*  u_pre  = nbuf;

  const dim3 Gw1(CH / 128, 8), Gw2(CH / 128, 2);
  auto TR = [&](const float* s, int K, int Nc) {
    transpose_k<<<dim3(Nc / 32, K / 32), B256, 0, stream>>>(s, wt, K, Nc, 0, 0);
  };

  for (int t = 0; t < 3; ++t) {
    for (int c = 0; c < N3 / CH; ++c) {
      const long r0 = (long)t * N3 + (long)c * CH;
      const float* xC   = agent_x + r0 * 256;
      float*       outC = outp + r0 * 256;

      cast_k<<<CH / 4, B256, 0, stream>>>(xC, xbf);
      TR(self_W + (long)t * 65536, 256, 256);
      gemm_k<EPI_RELU_BIAS><<<Gw2, B256, 0, stream>>>(
          xbf, 256, wt, 256, 0, self_b + t * 256, 0, nullptr, bbuf, 256, nullptr, nullptr, 256, 256);
      TR(out_W + (long)t * 262144 + 0 * 65536, 256, 256);
      gemm_k<EPI_ACC_INIT><<<Gw2, B256, 0, stream>>>(
          bbuf, 256, wt, 256, 0, out_b + t * 256, 0, outF32, nullptr, 0, nullptr, nullptr, 256, 256);

      ln_cat3_k<<<CH / 4, B256, 0, stream>>>(lane_x, xC, l2a_src + r0,
                                             l2a_ln_s, l2a_ln_b, nbuf);
      TR(l2a_w1, 768, 1024);
      gemm_k<EPI_RELU_BIAS><<<Gw1, B256, 0, stream>>>(
          nbuf, 768, wt, 768, 0, l2a_b1, 0, nullptr, h1, 1024, nullptr, nullptr, 768, 1024);
      TR(l2a_w2, 1024, 256);
      gemm_k<EPI_BIAS><<<Gw2, B256, 0, stream>>>(
          h1, 1024, wt, 1024, 0, l2a_b2, 0, nullptr, bbuf, 256, nullptr, nullptr, 1024, 256);
      TR(out_W + (long)t * 262144 + 1 * 65536, 256, 256);
      gemm_k<EPI_ACC_ADD><<<Gw2, B256, 0, stream>>>(
          bbuf, 256, wt, 256, 0, nullptr, 0, outF32, nullptr, 0, nullptr, nullptr, 256, 256);

      ln_cat2_k<<<CH / 4, B256, 0, stream>>>(poly_x, xC, g2a_src + r0,
                                             g2a_ln_s, g2a_ln_b, nbuf);
      TR(g2a_w1, 512, 1024);
      gemm_k<EPI_RELU_BIAS><<<Gw1, B256, 0, stream>>>(
          nbuf, 512, wt, 512, 0, g2a_b1, 0, nullptr, h1, 1024, nullptr, nullptr, 512, 1024);
      TR(g2a_w2, 1024, 256);
      gemm_k<EPI_BIAS><<<Gw2, B256, 0, stream>>>(
          h1, 1024, wt, 1024, 0, g2a_b2, 0, nullptr, bbuf, 256, nullptr, nullptr, 1024, 256);
      TR(out_W + (long)t * 262144 + 2 * 65536, 256, 256);
      gemm_k<EPI_ACC_ADD><<<Gw2, B256, 0, stream>>>(
          bbuf, 256, wt, 256, 0, nullptr, 0, outF32, nullptr, 0, nullptr, nullptr, 256, 256);

      for (int s = 0; s < 3; ++s) {
        ln_cat3_k<<<CH / 4, B256, 0, stream>>>(
            agent_x, xC, other_src + (long)s * N_AG + r0,
            oth_ln_s + s * 768, oth_ln_b + s * 768, nbuf);
        TR(oth_w1 + (long)s * 786432, 768, 1024);
        gemm_k<EPI_RELU_BIAS><<<Gw1, B256, 0, stream>>>(
            nbuf, 768, wt, 768, 0, oth_b1 + s * 1024, 0, nullptr, h1, 1024, nullptr, nullptr, 768, 1024);
        TR(oth_w2 + (long)s * 262144, 1024, 256);
        gemm_k<EPI_BIAS><<<Gw2, B256, 0, stream>>>(
            h1, 1024, wt, 1024, 0, oth_b2 + s * 256, 0, nullptr, bbuf, 256, nullptr, nullptr, 1024, 256);
        TR(out_W + (long)t * 262144 + 3 * 65536, 256, 256);
        gemm_k<EPI_ACC_ADD><<<Gw2, B256, 0, stream>>>(
            bbuf, 256, wt, 256, 0, nullptr, 0, outF32, nullptr, 0, nullptr, nullptr, 256, 256);
      }

      ln_ffn_k<<<CH / 4, B256, 0, stream>>>(outF32, ffn_ln_s + t * 256,
                                            ffn_ln_b + t * 256, ybuf, 0);
      TR(ffn_w1 + (long)t * 262144, 256, 1024);
      gemm_k<EPI_BIAS><<<Gw1, B256, 0, stream>>>(
          ybuf, 256, wt, 256, 0, ffn_b1 + t * 1024, 0, nullptr, g_pre, 1024, nullptr, nullptr, 256, 1024);
      TR(ffn_w3 + (long)t * 262144, 256, 1024);
      gemm_k<EPI_BIAS><<<Gw1, B256, 0, stream>>>(
          ybuf, 256, wt, 256, 0, ffn_b3 + t * 1024, 0, nullptr, u_pre, 1024, nullptr, nullptr, 256, 1024);
      silu_mul_k<<<CH, B256, 0, stream>>>(g_pre, u_pre);
      TR(ffn_w2 + (long)t * 262144, 1024, 256);
      gemm_k<EPI_FINAL><<<Gw2, B256, 0, stream>>>(
          g_pre, 1024, wt, 1024, 0, ffn_b2 + t * 256, 0, outF32, nullptr, 256, xC, outC, 1024, 256);
    }
  }
}